// Round 4
// baseline (297.102 us; speedup 1.0000x reference)
//
#include <hip/hip_runtime.h>
#include <hip/hip_bf16.h>

// PrimaryCaps fused 1x1 convs -> per-n GEMM: Out[544,1024] = W[544,512] * X_n[512,1024]
// R6: m97-shape waves + fully hand-counted pipeline, opaque to the compiler.
//  - 256 thr, 4 waves x (64x64) quadrant, acc 4x4, BK=32: 16 MFMA per wave-iter
//    (2x R5), half the barriers per FLOP. 128x128 tile, same XCD-grouped grid.
//  - Frag reads are inline-asm ds_read_b128 + lgkmcnt(0) + sched_barrier(0)
//    (rule #18): the compiler has no C++ read of ldsA/ldsB, so it cannot insert
//    a conservative vmcnt(0) drain against the glds writes (R5's suspected killer).
//  - Counted waits, deterministic queue (empty-asm fences pin VMEM issue order):
//      iter it: issue A-glds(it+1)[2] | fence | issue X-loads(it+2)[16]
//               asm frag reads(it); lgkmcnt(0); sched_barrier; 16 MFMA
//               vmcnt(18)  -> retires X(it+1); pack -> ldsB[(it+1)&1]
//               vmcnt(16) lgkmcnt(0) s_barrier -> retires A(it+1) glds (cross-wave
//               visibility) while the 16 X(it+2) loads STAY IN FLIGHT across the
//               barrier: a full iteration of latency cover.
//  - A bf16 via prep_w ([640][512], L2-resident), glds16 direct, pre-swizzled src.
//  - X fp32 reg-staged (16 dw/thread), packed bf16 to swizzled LDS (proven 0-conflict).
// LDS 32 KB, ~150 regs -> __launch_bounds__(256,3): 3 blocks/CU, 12 waves/CU.

typedef __attribute__((ext_vector_type(8))) short short8;
typedef __attribute__((ext_vector_type(4))) float f32x4;

#define A_CH   512
#define HW     1024
#define N_B    64
#define O_POSE 512
#define O_ACT  32
#define O_TOT  544
#define O_PAD  640            // 5 o-tiles * 128
#define TO     128
#define TM     128
#define BK     32
#define NIT    (A_CH / BK)    // 16

__device__ __forceinline__ unsigned pk(float lo, float hi) {
    __hip_bfloat162 h = __float22bfloat162_rn(make_float2(lo, hi));
    return *reinterpret_cast<unsigned*>(&h);
}

__device__ __forceinline__ void glds16(const void* g, void* l) {
    __builtin_amdgcn_global_load_lds(
        (const __attribute__((address_space(1))) unsigned*)g,
        (__attribute__((address_space(3))) unsigned*)l, 16, 0, 0);
}

// ---- pre-kernel: W fp32 (512 pose ++ 32 act rows) -> bf16 [640][512] in ws,
// rows 544..639 zeroed. Fully rewritten every launch (re-poison safe).
__global__ __launch_bounds__(256) void prep_w(const float* __restrict__ Wp,
                                              const float* __restrict__ Wa,
                                              unsigned short* __restrict__ Wb) {
    const int r = blockIdx.x;
    const int c = threadIdx.x * 2;
    float2 v = make_float2(0.f, 0.f);
    if (r < O_POSE)     v = *(const float2*)(Wp + (size_t)r * A_CH + c);
    else if (r < O_TOT) v = *(const float2*)(Wa + (size_t)(r - O_POSE) * A_CH + c);
    __hip_bfloat162 h = __float22bfloat162_rn(v);
    *(unsigned*)(Wb + (size_t)r * A_CH + c) = *reinterpret_cast<unsigned*>(&h);
}

__global__ __launch_bounds__(256, 3) void caps_gemm(
    const float* __restrict__ x,            // [64,512,32,32] fp32
    const unsigned short* __restrict__ Wb,  // [640,512] bf16 (padded)
    const float* __restrict__ bp,           // [512]
    const float* __restrict__ ba,           // [32]
    float* __restrict__ out)                // poses [64,512,1024] ++ act [64,32,1024]
{
    __shared__ __align__(16) short ldsA[2][TO * BK];   // 2 x 8 KB
    __shared__ __align__(16) short ldsB[2][TM * BK];   // 2 x 8 KB

    const int tid = threadIdx.x;

    // ---- XCD-grouped decode: the 5 o-blocks of one (m,n) stripe -> same XCD.
    const int lin  = blockIdx.x;
    const int xcd  = lin & 7;
    const int slot = lin >> 3;              // 0..319 per XCD
    const int ob   = slot % 5;
    const int mnid = (slot / 5) * 8 + xcd;  // 0..511
    const int m0   = (mnid & 7) * TM;
    const int n    = mnid >> 3;
    const int o0   = ob * TO;

    // ---- A staging (glds): dest linear tid*16B -> row tid>>2, slot tid&3;
    // second glds covers rows 64..127 (same swizzle: (r+64)>>1 & 3 == r>>1 & 3).
    const int arow = tid >> 2;
    const int aslt = tid & 3;
    const unsigned short* asrc1 =
        Wb + (size_t)(o0 + arow) * A_CH + ((aslt ^ ((arow >> 1) & 3)) * 8);
    const unsigned short* asrc2 = asrc1 + (size_t)64 * A_CH;

    // ---- X staging: m = tid&127, k-group kg = tid>>7 (octet pair {2kg,2kg+1}).
    // 16 dword loads per tile (wave instr = 64 consecutive m = 256B), 2 b128 writes.
    const int sm  = tid & 127;
    const int kg  = tid >> 7;
    const float* sbase = x + (size_t)n * A_CH * HW + m0 + sm;
    const int swz = (sm >> 1) & 3;
    const int wr0 = sm * BK + (((2 * kg)     ^ swz) * 8);
    const int wr1 = sm * BK + (((2 * kg + 1) ^ swz) * 8);

    float xr[2][16];                        // 2-deep prefetch banks

    // ---- wave w -> 64x64 quadrant: rows wo.., cols wm..
    const int lane = tid & 63;
    const int w    = tid >> 6;
    const int wo   = (w >> 1) * 64;
    const int wm   = (w & 1) * 64;
    const int l16  = lane & 15;
    const int g    = lane >> 4;

    // LDS byte addresses for asm ds_read (low 32 bits of generic shared addr = offset)
    const unsigned baseA = (unsigned)(uintptr_t)&ldsA[0][0];
    const unsigned baseB = (unsigned)(uintptr_t)&ldsB[0][0];
    unsigned aoff[4], boff[4];
#pragma unroll
    for (int f = 0; f < 4; ++f) {
        const int r = wo + f * 16 + l16;
        aoff[f] = baseA + (unsigned)(r * BK + ((g ^ ((r >> 1) & 3)) * 8)) * 2u;
        const int c = wm + f * 16 + l16;
        boff[f] = baseB + (unsigned)(c * BK + ((g ^ ((c >> 1) & 3)) * 8)) * 2u;
    }

    f32x4 acc[4][4] = {};                   // 64 AGPR

    // ---- prologue: queue = A0[2] | X0[16] | X1[16]  (fences pin the order)
    glds16(asrc1, &ldsA[0][tid * 8]);
    glds16(asrc2, &ldsA[0][2048 + tid * 8]);
    asm volatile("" ::: "memory");
#pragma unroll
    for (int j = 0; j < 16; ++j) xr[0][j] = sbase[(size_t)(kg * 16 + j) * HW];
    asm volatile("" ::: "memory");
#pragma unroll
    for (int j = 0; j < 16; ++j) xr[1][j] = sbase[(size_t)(BK + kg * 16 + j) * HW];
    asm volatile("s_waitcnt vmcnt(16)" ::: "memory");   // A0 + X0 retired
    {
        short8 v0, v1;
#pragma unroll
        for (int j = 0; j < 4; ++j) {
            ((unsigned*)&v0)[j] = pk(xr[0][2 * j],     xr[0][2 * j + 1]);
            ((unsigned*)&v1)[j] = pk(xr[0][8 + 2 * j], xr[0][9 + 2 * j]);
        }
        *(short8*)&ldsB[0][wr0] = v0;
        *(short8*)&ldsB[0][wr1] = v1;
    }
    asm volatile("s_waitcnt lgkmcnt(0)\ns_barrier" ::: "memory");

#pragma unroll
    for (int it = 0; it < NIT; ++it) {
        const int cur = it & 1;
        // a. issue A(it+1) glds, then (fenced) X(it+2) loads -> deterministic queue
        if (it + 1 < NIT) {
            glds16(asrc1 + (it + 1) * BK, &ldsA[cur ^ 1][tid * 8]);
            glds16(asrc2 + (it + 1) * BK, &ldsA[cur ^ 1][2048 + tid * 8]);
            asm volatile("" ::: "memory");
        }
        if (it + 2 < NIT) {
#pragma unroll
            for (int j = 0; j < 16; ++j)
                xr[cur][j] = sbase[(size_t)((it + 2) * BK + kg * 16 + j) * HW];
        }
        // b. opaque frag reads (no compiler-inserted vmcnt possible)
        short8 aF[4], bF[4];
#pragma unroll
        for (int f = 0; f < 4; ++f)
            asm volatile("ds_read_b128 %0, %1" : "=v"(aF[f]) : "v"(aoff[f] + cur * 8192u));
#pragma unroll
        for (int f = 0; f < 4; ++f)
            asm volatile("ds_read_b128 %0, %1" : "=v"(bF[f]) : "v"(boff[f] + cur * 8192u));
        asm volatile("s_waitcnt lgkmcnt(0)" ::: "memory");
        __builtin_amdgcn_sched_barrier(0);               // rule #18: pin MFMAs after wait
        // c. 16 MFMA
#pragma unroll
        for (int fo = 0; fo < 4; ++fo)
#pragma unroll
            for (int fm = 0; fm < 4; ++fm)
                acc[fo][fm] = __builtin_amdgcn_mfma_f32_16x16x32_bf16(
                    aF[fo], bF[fm], acc[fo][fm], 0, 0, 0);
        // d. counted retire of X(it+1); pack; barrier retires A(it+1) but keeps
        //    X(it+2)'s 16 loads in flight across it.
        if (it + 1 < NIT) {
            if (it + 2 < NIT) asm volatile("s_waitcnt vmcnt(18)" ::: "memory");
            else              asm volatile("s_waitcnt vmcnt(2)"  ::: "memory");
            const int b = cur ^ 1;          // X(it+1) lives in bank (it+1)&1
            short8 v0, v1;
#pragma unroll
            for (int j = 0; j < 4; ++j) {
                ((unsigned*)&v0)[j] = pk(xr[b][2 * j],     xr[b][2 * j + 1]);
                ((unsigned*)&v1)[j] = pk(xr[b][8 + 2 * j], xr[b][9 + 2 * j]);
            }
            *(short8*)&ldsB[b][wr0] = v0;
            *(short8*)&ldsB[b][wr1] = v1;
            if (it + 2 < NIT)
                asm volatile("s_waitcnt vmcnt(16) lgkmcnt(0)\ns_barrier" ::: "memory");
            else
                asm volatile("s_waitcnt vmcnt(0) lgkmcnt(0)\ns_barrier" ::: "memory");
        }
    }

    // ---- epilogue: C/D layout col = lane&15, row = (lane>>4)*4 + reg
    float* actOut = out + (size_t)N_B * O_POSE * HW;
    const size_t poseN = (size_t)n * O_POSE * HW;
    const size_t actN  = (size_t)n * O_ACT * HW;
#pragma unroll
    for (int fo = 0; fo < 4; ++fo) {
#pragma unroll
        for (int i = 0; i < 4; ++i) {
            const int R = o0 + wo + fo * 16 + g * 4 + i;
            if (R >= O_TOT) continue;              // padded rows 544..639
            if (R < O_POSE) {
                const float bias = bp[R];
#pragma unroll
                for (int fm = 0; fm < 4; ++fm) {
                    const int cc = m0 + wm + fm * 16 + l16;
                    __builtin_nontemporal_store(acc[fo][fm][i] + bias,
                                                &out[poseN + (size_t)R * HW + cc]);
                }
            } else {
                const float bias = ba[R - O_POSE];
#pragma unroll
                for (int fm = 0; fm < 4; ++fm) {
                    const int cc = m0 + wm + fm * 16 + l16;
                    const float v = acc[fo][fm][i] + bias;
                    __builtin_nontemporal_store(1.0f / (1.0f + __expf(-v)),
                                                &actOut[actN + (size_t)(R - O_POSE) * HW + cc]);
                }
            }
        }
    }
}

extern "C" void kernel_launch(void* const* d_in, const int* in_sizes, int n_in,
                              void* d_out, int out_size, void* d_ws, size_t ws_size,
                              hipStream_t stream) {
    (void)in_sizes; (void)n_in; (void)out_size; (void)ws_size;
    const float* x  = (const float*)d_in[0];
    const float* Wp = (const float*)d_in[1];
    const float* bp = (const float*)d_in[2];
    const float* Wa = (const float*)d_in[3];
    const float* ba = (const float*)d_in[4];
    unsigned short* Wb = (unsigned short*)d_ws;   // needs 640*512*2 = 655,360 B

    prep_w<<<dim3(O_PAD), dim3(256), 0, stream>>>(Wp, Wa, Wb);
    // 8 m-tiles * 5 o-tiles * 64 n = 2560 blocks, XCD-grouped decode in-kernel
    caps_gemm<<<dim3(8 * 5 * N_B), dim3(256), 0, stream>>>(x, Wb, bp, ba, (float*)d_out);
}